// Round 1
// 915.459 us; speedup vs baseline: 1.3770x; 1.3770x over previous
//
#include <hip/hip_runtime.h>

#define NE 1000000
#define NN 50000
#define D 64

// ---------------------------------------------------------------------------
// zero the atomic accumulators: acc_y[NN*D] and denom[NN]
__global__ __launch_bounds__(256) void k_init(float4* __restrict__ acc4,
                                              float* __restrict__ denom){
  int i = blockIdx.x*256 + threadIdx.x;
  if (i < NN*D/4) acc4[i] = make_float4(0.f,0.f,0.f,0.f);
  if (i < NN)     denom[i] = 0.f;
}

// ---------------------------------------------------------------------------
// h_self = x_v@W_vv^T + b_vv -> h_v ;  p_av = x_v@W_av^T
// wave-per-node, lane = output column j. Weight ROWS (contiguous) in VGPRs;
// x row broadcast via per-wave 256B LDS buffer (uniform ds_read_b128).
__global__ __launch_bounds__(256) void k_node(const float* __restrict__ x_v,
    const float* __restrict__ W_vv, const float* __restrict__ b_vv,
    const float* __restrict__ W_av, float* __restrict__ h_v,
    float* __restrict__ p_av){
  __shared__ float4 xrow[4][2][16];          // [wave][parity][16 x float4]
  int lane = threadIdx.x & 63;
  int wv   = threadIdx.x >> 6;
  int wid  = __builtin_amdgcn_readfirstlane(blockIdx.x*4 + wv);
  int nw   = gridDim.x*4;
  float4 wvv[16], wav[16];
  #pragma unroll
  for (int q = 0; q < 16; q++){
    wvv[q] = *(const float4*)(W_vv + lane*D + q*4);   // W_vv[lane][4q..4q+3]
    wav[q] = *(const float4*)(W_av + lane*D + q*4);
  }
  float bv = b_vv[lane];
  int p = 0;
  for (int n = wid; n < NN; n += nw, p ^= 1){
    float xv = x_v[(size_t)n*D + lane];
    ((float*)xrow[wv][p])[lane] = xv;        // same-wave DS ops are in-order
    float a0=0.f,a1=0.f,b0=0.f,b1=0.f;
    #pragma unroll
    for (int q = 0; q < 16; q++){
      float4 x4 = xrow[wv][p][q];            // uniform addr -> broadcast b128
      a0 += x4.x*wvv[q].x; a1 += x4.y*wvv[q].y;
      a0 += x4.z*wvv[q].z; a1 += x4.w*wvv[q].w;
      b0 += x4.x*wav[q].x; b1 += x4.y*wav[q].y;
      b0 += x4.z*wav[q].z; b1 += x4.w*wav[q].w;
    }
    h_v[(size_t)n*D + lane]  = a0+a1+bv;
    p_av[(size_t)n*D + lane] = b0+b1;
  }
}

// ---------------------------------------------------------------------------
// Fully fused edge pass. wave-per-edge, lane = column.
//   h_a[e]   = x_a[e]@W_aa^T + b_aa + p_av[src] + p_av[dst]
//   w        = exp(x_a[e]·W_att + b_att)        (no max-sub: |logit| <~ 3.1)
//   denom[d] += w ; acc_y[d][:] += w * x_a[e]   (HW f32 atomics)
__global__ __launch_bounds__(256) void k_edge(const float* __restrict__ x_a,
    const int* __restrict__ src, const int* __restrict__ dst,
    const float* __restrict__ W_aa, const float* __restrict__ b_aa,
    const float* __restrict__ W_att, const float* __restrict__ b_att,
    const float* __restrict__ p_av, float* __restrict__ h_a,
    float* __restrict__ acc_y, float* __restrict__ denom){
  __shared__ float4 xrow[4][2][16];
  int lane = threadIdx.x & 63;
  int wv   = threadIdx.x >> 6;
  int wid  = __builtin_amdgcn_readfirstlane(blockIdx.x*4 + wv);
  int nw   = gridDim.x*4;
  float4 waa[16];
  #pragma unroll
  for (int q = 0; q < 16; q++)
    waa[q] = *(const float4*)(W_aa + lane*D + q*4);   // W_aa[lane][4q..4q+3]
  float ba   = b_aa[lane];
  float wt   = W_att[lane];
  float batt = b_att[0];
  int p = 0;
  for (int e = wid; e < NE; e += nw, p ^= 1){
    int s  = src[e];                          // e uniform -> scalar loads
    int d2 = dst[e];
    float xv = x_a[(size_t)e*D + lane];       // 256B coalesced
    float ps = p_av[(size_t)s*D  + lane];
    float pd = p_av[(size_t)d2*D + lane];
    ((float*)xrow[wv][p])[lane] = xv;
    // attention logit: butterfly reduce of xv*wt over the 64 lanes
    float el = xv*wt;
    #pragma unroll
    for (int m = 32; m >= 1; m >>= 1) el += __shfl_xor(el, m, 64);
    float w = __expf(el + batt);
    // GEMV: h_a[e][lane] = sum_k x[e][k] * W_aa[lane][k]
    float a0=0.f,a1=0.f,a2=0.f,a3=0.f;
    #pragma unroll
    for (int q = 0; q < 16; q++){
      float4 x4 = xrow[wv][p][q];             // uniform broadcast b128
      a0 += x4.x*waa[q].x; a1 += x4.y*waa[q].y;
      a2 += x4.z*waa[q].z; a3 += x4.w*waa[q].w;
    }
    h_a[(size_t)e*D + lane] = a0+a1+a2+a3 + ba + ps + pd;
    unsafeAtomicAdd(&acc_y[(size_t)d2*D + lane], w*xv);   // 1 instr / edge
    if (lane == 0) unsafeAtomicAdd(&denom[d2], w);
  }
}

// ---------------------------------------------------------------------------
// h_v[n] += W_va @ (acc_y[n] / denom[n])
__global__ __launch_bounds__(256) void k_finish(const float* __restrict__ acc_y,
    const float* __restrict__ denom, const float* __restrict__ W_va,
    float* __restrict__ h_v){
  __shared__ float4 yrow[4][2][16];
  int lane = threadIdx.x & 63;
  int wv   = threadIdx.x >> 6;
  int wid  = __builtin_amdgcn_readfirstlane(blockIdx.x*4 + wv);
  int nw   = gridDim.x*4;
  float4 wva[16];
  #pragma unroll
  for (int q = 0; q < 16; q++)
    wva[q] = *(const float4*)(W_va + lane*D + q*4);
  int p = 0;
  for (int n = wid; n < NN; n += nw, p ^= 1){
    float dn  = denom[n];
    float inv = (dn > 0.f) ? 1.f/dn : 0.f;    // empty segment -> zero message
    float yv  = acc_y[(size_t)n*D + lane] * inv;
    ((float*)yrow[wv][p])[lane] = yv;
    float a0=0.f,a1=0.f,a2=0.f,a3=0.f;
    #pragma unroll
    for (int q = 0; q < 16; q++){
      float4 y4 = yrow[wv][p][q];
      a0 += y4.x*wva[q].x; a1 += y4.y*wva[q].y;
      a2 += y4.z*wva[q].z; a3 += y4.w*wva[q].w;
    }
    h_v[(size_t)n*D + lane] += a0+a1+a2+a3;
  }
}

// ---------------------------------------------------------------------------
extern "C" void kernel_launch(void* const* d_in, const int* in_sizes, int n_in,
                              void* d_out, int out_size, void* d_ws, size_t ws_size,
                              hipStream_t stream){
  const float* x_v   = (const float*)d_in[0];
  const float* x_a   = (const float*)d_in[1];
  const int*   arc   = (const int*)  d_in[2];
  const float* W_vv  = (const float*)d_in[3];
  const float* b_vv  = (const float*)d_in[4];
  const float* W_va  = (const float*)d_in[5];
  const float* W_att = (const float*)d_in[6];
  const float* b_att = (const float*)d_in[7];
  const float* W_aa  = (const float*)d_in[8];
  const float* b_aa  = (const float*)d_in[9];
  const float* W_av  = (const float*)d_in[10];

  float* out = (float*)d_out;
  float* h_v = out;                         // [NN, D]
  float* h_a = out + (size_t)NN*D;          // [NE, D]

  // workspace: acc_y[NN*D] | denom[NN] | p_av[NN*D]   (~25.8 MB)
  float* wsf   = (float*)d_ws;
  float* acc_y = wsf;
  float* denom = wsf + (size_t)NN*D;
  float* p_av  = wsf + (size_t)NN*D + NN;

  const int* srcp = arc;
  const int* dstp = arc + NE;

  hipLaunchKernelGGL(k_init,   dim3((NN*D/4 + 255)/256), dim3(256), 0, stream,
                     (float4*)acc_y, denom);
  hipLaunchKernelGGL(k_node,   dim3(768),  dim3(256), 0, stream,
                     x_v, W_vv, b_vv, W_av, h_v, p_av);
  hipLaunchKernelGGL(k_edge,   dim3(2048), dim3(256), 0, stream,
                     x_a, srcp, dstp, W_aa, b_aa, W_att, b_att, p_av, h_a,
                     acc_y, denom);
  hipLaunchKernelGGL(k_finish, dim3(768),  dim3(256), 0, stream,
                     acc_y, denom, W_va, h_v);
}